// Round 1
// 607.331 us; speedup vs baseline: 1.0091x; 1.0091x over previous
//
#include <hip/hip_runtime.h>

typedef unsigned short u16;
typedef unsigned int   u32;
typedef short  s16x8 __attribute__((ext_vector_type(8)));
typedef float  f32x4 __attribute__((ext_vector_type(4)));

__device__ __forceinline__ u16 f2bf(float f) {
    union { float f; u32 i; } x; x.f = f;
    u32 r = x.i + 0x7FFFu + ((x.i >> 16) & 1u);   // RNE
    return (u16)(r >> 16);
}

// async global->LDS, 16B per lane; lds base wave-uniform (HW adds lane*16)
__device__ __forceinline__ void gld16(const void* g, void* l) {
    __builtin_amdgcn_global_load_lds((const __attribute__((address_space(1))) void*)g,
                                     (__attribute__((address_space(3))) void*)l,
                                     16, 0, 0);
}

// ---------------------------------------------------------------------------
// elementwise fp32 -> bf16 cast
// ---------------------------------------------------------------------------
__global__ __launch_bounds__(256)
void cast_bf16(const float* __restrict__ in, u16* __restrict__ out, int n4) {
    int g = blockIdx.x * 256 + threadIdx.x;
    if (g >= n4) return;
    float4 v = ((const float4*)in)[g];
    ushort4 o; o.x = f2bf(v.x); o.y = f2bf(v.y); o.z = f2bf(v.z); o.w = f2bf(v.w);
    ((ushort4*)out)[g] = o;
}

// ---------------------------------------------------------------------------
// B[K][N] fp32 -> Bt[N][K] bf16, 32x32 LDS tile. grid(N/32, K/32)
// ---------------------------------------------------------------------------
__global__ __launch_bounds__(256)
void tconv(const float* __restrict__ B, u16* __restrict__ Bt, int K, int N) {
    __shared__ float T[32][33];
    int n0 = blockIdx.x * 32, k0 = blockIdx.y * 32;
    int t = threadIdx.x;
    int r = t >> 3, c4 = (t & 7) * 4;
    float4 v = *(const float4*)&B[(size_t)(k0 + r) * N + n0 + c4];
    T[r][c4 + 0] = v.x; T[r][c4 + 1] = v.y; T[r][c4 + 2] = v.z; T[r][c4 + 3] = v.w;
    __syncthreads();
    ushort4 o;
    o.x = f2bf(T[c4 + 0][r]); o.y = f2bf(T[c4 + 1][r]);
    o.z = f2bf(T[c4 + 2][r]); o.w = f2bf(T[c4 + 3][r]);
    *(ushort4*)&Bt[(size_t)(n0 + r) * K + k0 + c4] = o;
}

// ---------------------------------------------------------------------------
// cache_k fp32 [t][8][128] -> Kc bf16 [kh][4096_t][128] (tokens 0..2047)
// ---------------------------------------------------------------------------
__global__ __launch_bounds__(256)
void kcache_conv(const float* __restrict__ ck, u16* __restrict__ Kc) {
    int g = blockIdx.x * 256 + threadIdx.x;
    int d = (g & 31) * 4, kh = (g >> 5) & 7, t = g >> 8;
    float4 v = *(const float4*)&ck[(size_t)t * 1024 + kh * 128 + d];
    ushort4 o; o.x = f2bf(v.x); o.y = f2bf(v.y); o.z = f2bf(v.z); o.w = f2bf(v.w);
    *(ushort4*)&Kc[(size_t)kh * 524288 + (size_t)t * 128 + d] = o;
}

// ---------------------------------------------------------------------------
// cache_v fp32 [t][8][128] -> Vt bf16 [kh][128_hd][4096_t] (tokens 0..2047)
// ---------------------------------------------------------------------------
__global__ __launch_bounds__(256)
void vcache_conv(const float* __restrict__ cv, u16* __restrict__ Vt) {
    __shared__ float T[32][33];
    int t0 = blockIdx.x * 32, d0 = blockIdx.y * 32, kh = blockIdx.z;
    int t = threadIdx.x;
    int r = t >> 3, c4 = (t & 7) * 4;
    float4 v = *(const float4*)&cv[(size_t)(t0 + r) * 1024 + kh * 128 + d0 + c4];
    T[r][c4 + 0] = v.x; T[r][c4 + 1] = v.y; T[r][c4 + 2] = v.z; T[r][c4 + 3] = v.w;
    __syncthreads();
    ushort4 o;
    o.x = f2bf(T[c4 + 0][r]); o.y = f2bf(T[c4 + 1][r]);
    o.z = f2bf(T[c4 + 2][r]); o.w = f2bf(T[c4 + 3][r]);
    *(ushort4*)&Vt[(size_t)(kh * 128 + d0 + r) * 4096 + t0 + c4] = o;
}

// ---------------------------------------------------------------------------
// Shared MFMA GEMM main loop: acc[4][4] += A[m0..+128][K] @ Bt[0..128][K]^T.
// 128x128 tile, BK=32, gld16 staging, XOR-swizzled LDS (verified R3-R5).
// ---------------------------------------------------------------------------
__device__ __forceinline__ void gemm_core(const u16* __restrict__ A,
                                          const u16* __restrict__ Bt,
                                          int K, int m0,
                                          u16* As, u16* Bs, f32x4 acc[4][4])
{
    const int tid = threadIdx.x;
    const int lane = tid & 63, w = tid >> 6;
    const int quad = lane >> 4, l15 = lane & 15;
    const int mw = (w >> 1) * 64, nw = (w & 1) * 64;
    const int lrow = tid >> 2;
    const int lcol = ((tid & 3) ^ (lrow & 3)) * 8;
    const int rsw = l15 & 3;

    for (int k0 = 0; k0 < K; k0 += 32) {
        __syncthreads();
        gld16(A  + (size_t)(m0 +      lrow) * K + k0 + lcol, &As[w * 512]);
        gld16(A  + (size_t)(m0 + 64 + lrow) * K + k0 + lcol, &As[2048 + w * 512]);
        gld16(Bt + (size_t)(           lrow) * K + k0 + lcol, &Bs[w * 512]);
        gld16(Bt + (size_t)(      64 + lrow) * K + k0 + lcol, &Bs[2048 + w * 512]);
        __syncthreads();
        s16x8 af[4], bf[4];
        #pragma unroll
        for (int i = 0; i < 4; ++i)
            af[i] = *(const s16x8*)&As[(mw + i * 16 + l15) * 32 + (quad ^ rsw) * 8];
        #pragma unroll
        for (int j = 0; j < 4; ++j)
            bf[j] = *(const s16x8*)&Bs[(nw + j * 16 + l15) * 32 + (quad ^ rsw) * 8];
        #pragma unroll
        for (int i = 0; i < 4; ++i)
            #pragma unroll
            for (int j = 0; j < 4; ++j)
                acc[i][j] = __builtin_amdgcn_mfma_f32_16x16x32_bf16(
                    af[i], bf[j], acc[i][j], 0, 0, 0);
    }
}

// ---------------------------------------------------------------------------
// Fused QKV GEMM: N = 4096(Q) + 1024(K) + 1024(V) = 6144, grid(48,16).
// ---------------------------------------------------------------------------
__global__ __launch_bounds__(256, 2)
void gemm_qkv(const u16* __restrict__ A, const u16* __restrict__ Wq,
              const u16* __restrict__ Wk, const u16* __restrict__ Wv,
              u16* __restrict__ Qw, u16* __restrict__ Kc, u16* __restrict__ Vt,
              const float* __restrict__ rope)
{
    __shared__ u16 As[128 * 32];
    __shared__ u16 Bs[128 * 32];
    const int m0 = blockIdx.y * 128, n0 = blockIdx.x * 128;

    const u16* Bt;
    if (n0 < 4096)       Bt = Wq + (size_t)n0 * 4096;
    else if (n0 < 5120)  Bt = Wk + (size_t)(n0 - 4096) * 4096;
    else                 Bt = Wv + (size_t)(n0 - 5120) * 4096;

    f32x4 acc[4][4];
    #pragma unroll
    for (int i = 0; i < 4; ++i)
        #pragma unroll
        for (int j = 0; j < 4; ++j) acc[i][j] = (f32x4)0.f;

    gemm_core(A, Bt, 4096, m0, As, Bs, acc);

    const int lane = threadIdx.x & 63, w = threadIdx.x >> 6;
    const int quad = lane >> 4, l15 = lane & 15;
    const int mw = (w >> 1) * 64, nw = (w & 1) * 64;

    #pragma unroll
    for (int i = 0; i < 4; ++i) {
        #pragma unroll
        for (int j = 0; j < 4; ++j) {
            int mm = m0 + mw + i * 16 + quad * 4;
            int nn = n0 + nw + j * 16 + l15;
            if (nn < 4096) {
                #pragma unroll
                for (int r = 0; r < 4; ++r)
                    Qw[(size_t)(mm + r) * 4096 + nn] =
                        f2bf(acc[i][j][r] * rope[(size_t)(mm + r) * 128 + (nn & 127)]
                             * 0.08838834764831845f);
            } else if (nn < 5120) {
                #pragma unroll
                for (int r = 0; r < 4; ++r)
                    Kc[(size_t)((nn - 4096) >> 7) * 524288
                       + (size_t)(2048 + mm + r) * 128 + (nn & 127)] =
                        f2bf(acc[i][j][r] * rope[(size_t)(mm + r) * 128 + (nn & 127)]);
            } else {
                ushort4 o;
                o.x = f2bf(acc[i][j][0]); o.y = f2bf(acc[i][j][1]);
                o.z = f2bf(acc[i][j][2]); o.w = f2bf(acc[i][j][3]);
                *(ushort4*)&Vt[(size_t)(nn - 5120) * 4096 + 2048 + mm] = o;
            }
        }
    }
}

// ---------------------------------------------------------------------------
// Output GEMM: out = AO @ wo^T, fp32 out. grid(32,16).
// ---------------------------------------------------------------------------
__global__ __launch_bounds__(256, 2)
void gemm_wo(const u16* __restrict__ A, const u16* __restrict__ Bt,
             float* __restrict__ C)
{
    __shared__ u16 As[128 * 32];
    __shared__ u16 Bs[128 * 32];
    const int m0 = blockIdx.y * 128, n0 = blockIdx.x * 128;

    f32x4 acc[4][4];
    #pragma unroll
    for (int i = 0; i < 4; ++i)
        #pragma unroll
        for (int j = 0; j < 4; ++j) acc[i][j] = (f32x4)0.f;

    gemm_core(A, Bt + (size_t)n0 * 4096, 4096, m0, As, Bs, acc);

    const int lane = threadIdx.x & 63, w = threadIdx.x >> 6;
    const int quad = lane >> 4, l15 = lane & 15;
    const int mw = (w >> 1) * 64, nw = (w & 1) * 64;

    #pragma unroll
    for (int i = 0; i < 4; ++i)
        #pragma unroll
        for (int j = 0; j < 4; ++j) {
            int mm = m0 + mw + i * 16 + quad * 4;
            int nn = n0 + nw + j * 16 + l15;
            #pragma unroll
            for (int r = 0; r < 4; ++r)
                C[(size_t)(mm + r) * 4096 + nn] = acc[i][j][r];
        }
}

// ---------------------------------------------------------------------------
// MFMA flash attention, T3-minimal 2-phase pipeline (R6):
//   - Q fragments hoisted to registers once (loop-invariant): kills 8
//     ds_read_b128/tile/wave + the padded Qs LDS buffer + its bank conflicts.
//   - K/V double-buffered in LDS; tile t+1's 16 gld16 issued right after the
//     top barrier of tile t; the vmcnt drain happens at the NEXT top
//     __syncthreads -> staging overlaps the whole S+softmax+PV body.
//   - Mid-tile Pb barrier is lgkmcnt-only (raw s_barrier, memory-clobber
//     fenced) so the in-flight global_load_lds are NOT drained there.
// LDS: 2*16K (Ks) + 2*16K (Vs) + 9216 (Pb) + 512 (Ls) = 75264 B -> 2 blk/CU.
// grid(32 heads x, 32 q-tiles y), 256 thr = 4 waves; 64 q/block, 64-key tiles.
// XOR-swizzled 16B chunks at staging (gld16 forbids padding), same XOR on
// frag reads -> 2-way conflicts (free, m136). Stateless softmax (exact).
// ---------------------------------------------------------------------------
__global__ __launch_bounds__(256, 2)
void attn_mfma(const u16* __restrict__ Qw, const u16* __restrict__ Kc,
               const u16* __restrict__ Vt, u16* __restrict__ AO)
{
    __shared__ u16 Ks[2][64 * 128];  // [buf][key][hd], rows 256B, swizzled
    __shared__ u16 Vs[2][128 * 64];  // [buf][hd][key], rows 128B, swizzled
    __shared__ u16 Pb[64 * 72];      // [q][key], padded stride 144B
    __shared__ float Ls[2][64];

    const int tid = threadIdx.x;
    const int lane = tid & 63, w = tid >> 6;
    const int quad = lane >> 4, l15 = lane & 15;
    const int h = blockIdx.x, kh = h >> 2;
    const int q0 = blockIdx.y * 64;
    const int kw = w & 1, qw = w >> 1;
    const size_t kvb = (size_t)kh * 524288;

    // Q fragments -> registers, once. qreg[n][ks] == old Qs frag (qf_n, ks).
    s16x8 qreg[2][4];
    #pragma unroll
    for (int n = 0; n < 2; ++n)
        #pragma unroll
        for (int ks = 0; ks < 4; ++ks)
            qreg[n][ks] = *(const s16x8*)&Qw[(size_t)(q0 + qw * 32 + n * 16 + l15) * 4096
                                             + h * 128 + ks * 32 + quad * 8];

    f32x4 o[2][4];
    #pragma unroll
    for (int m = 0; m < 2; ++m)
        #pragma unroll
        for (int n = 0; n < 4; ++n) o[m][n] = (f32x4)0.f;
    float lacc[2] = {0.f, 0.f};

    // staging roles (swizzled global column chunks)
    const int krow = tid >> 4, kcol = ((tid & 15) ^ (krow & 15)) * 8;
    const int vrow = tid >> 3, vcol = ((tid & 7) ^ (vrow & 7)) * 8;
    // frag-read swizzles
    const int ksw = l15, vsw = l15 & 7;

    const u16* kpg = Kc + kvb + (size_t)krow * 128 + kcol;
    const u16* vpg = Vt + kvb + (size_t)vrow * 4096 + vcol;

    const int kend = 2112 + q0;     // last needed key = 2048+q0+63

    // prologue: stage tile 0 into buffer 0 (drained at first top barrier)
    #pragma unroll
    for (int i = 0; i < 4; ++i)
        gld16(kpg + i * 2048, &Ks[0][i * 2048 + w * 512]);
    #pragma unroll
    for (int i = 0; i < 4; ++i)
        gld16(vpg + (size_t)i * 131072, &Vs[0][i * 2048 + w * 512]);

    int cur = 0;
    for (int t0 = 0; t0 < kend; t0 += 64, cur ^= 1) {
        // full drain: buf[cur] staged & visible; prior tile's LDS reads done
        __syncthreads();

        // issue next tile's staging into buf[cur^1]; stays in flight until
        // the NEXT top __syncthreads -> overlaps all compute below
        const int t1 = t0 + 64;
        if (t1 < kend) {
            #pragma unroll
            for (int i = 0; i < 4; ++i)
                gld16(kpg + (size_t)t1 * 128 + i * 2048,
                      &Ks[cur ^ 1][i * 2048 + w * 512]);
            #pragma unroll
            for (int i = 0; i < 4; ++i)
                gld16(vpg + (size_t)i * 131072 + t1,
                      &Vs[cur ^ 1][i * 2048 + w * 512]);
        }

        // ---- S phase: wave (kw,qw) -> keys [32kw,+32) x q [32qw,+32) ----
        f32x4 sc[2][2];
        sc[0][0] = (f32x4)0.f; sc[0][1] = (f32x4)0.f;
        sc[1][0] = (f32x4)0.f; sc[1][1] = (f32x4)0.f;
        #pragma unroll
        for (int ks = 0; ks < 4; ++ks) {
            int kc8 = (((ks * 4 + quad) ^ ksw) & 15) * 8;
            s16x8 kf0 = *(const s16x8*)&Ks[cur][(kw * 32 +      l15) * 128 + kc8];
            s16x8 kf1 = *(const s16x8*)&Ks[cur][(kw * 32 + 16 + l15) * 128 + kc8];
            sc[0][0] = __builtin_amdgcn_mfma_f32_16x16x32_bf16(kf0, qreg[0][ks], sc[0][0], 0, 0, 0);
            sc[0][1] = __builtin_amdgcn_mfma_f32_16x16x32_bf16(kf0, qreg[1][ks], sc[0][1], 0, 0, 0);
            sc[1][0] = __builtin_amdgcn_mfma_f32_16x16x32_bf16(kf1, qreg[0][ks], sc[1][0], 0, 0, 0);
            sc[1][1] = __builtin_amdgcn_mfma_f32_16x16x32_bf16(kf1, qreg[1][ks], sc[1][1], 0, 0, 0);
        }

        const bool maskt = (t0 + 63 > 2048 + q0);
        #pragma unroll
        for (int m2 = 0; m2 < 2; ++m2) {
            #pragma unroll
            for (int n2 = 0; n2 < 2; ++n2) {
                float e0 = __expf(sc[m2][n2][0]);
                float e1 = __expf(sc[m2][n2][1]);
                float e2 = __expf(sc[m2][n2][2]);
                float e3 = __expf(sc[m2][n2][3]);
                if (maskt) {
                    int key = t0 + kw * 32 + m2 * 16 + quad * 4;
                    int qv  = q0 + qw * 32 + n2 * 16 + l15;
                    if (key + 0 >= 2048 && key + 0 - 2048 > qv) e0 = 0.f;
                    if (key + 1 >= 2048 && key + 1 - 2048 > qv) e1 = 0.f;
                    if (key + 2 >= 2048 && key + 2 - 2048 > qv) e2 = 0.f;
                    if (key + 3 >= 2048 && key + 3 - 2048 > qv) e3 = 0.f;
                }
                lacc[n2] += (e0 + e1) + (e2 + e3);
                uint2 pk;
                pk.x = (u32)f2bf(e0) | ((u32)f2bf(e1) << 16);
                pk.y = (u32)f2bf(e2) | ((u32)f2bf(e3) << 16);
                *(uint2*)&Pb[(qw * 32 + n2 * 16 + l15) * 72 + kw * 32 + m2 * 16 + quad * 4] = pk;
            }
        }

        // Pb-ready barrier: DS ordering only -- do NOT drain vmcnt (the
        // next-tile gld16s must stay in flight across this barrier)
        asm volatile("s_waitcnt lgkmcnt(0)" ::: "memory");
        __builtin_amdgcn_s_barrier();
        asm volatile("" ::: "memory");

        // ---- PV phase: wave w -> hd [32w,+32) x all 64 q, k = 64 keys ----
        #pragma unroll
        for (int ks = 0; ks < 2; ++ks) {
            int vc8 = (((ks * 4 + quad) ^ vsw) & 7) * 8;
            s16x8 vf0 = *(const s16x8*)&Vs[cur][(w * 32 +      l15) * 64 + vc8];
            s16x8 vf1 = *(const s16x8*)&Vs[cur][(w * 32 + 16 + l15) * 64 + vc8];
            #pragma unroll
            for (int n = 0; n < 4; ++n) {
                s16x8 pf = *(const s16x8*)&Pb[(n * 16 + l15) * 72 + ks * 32 + quad * 8];
                o[0][n] = __builtin_amdgcn_mfma_f32_16x16x32_bf16(vf0, pf, o[0][n], 0, 0, 0);
                o[1][n] = __builtin_amdgcn_mfma_f32_16x16x32_bf16(vf1, pf, o[1][n], 0, 0, 0);
            }
        }
    }

    // L totals: reduce over quads, publish per (kw, q), sum the two kw halves
    lacc[0] += __shfl_xor(lacc[0], 16); lacc[0] += __shfl_xor(lacc[0], 32);
    lacc[1] += __shfl_xor(lacc[1], 16); lacc[1] += __shfl_xor(lacc[1], 32);
    if (lane < 16) {
        Ls[kw][qw * 32 +      lane] = lacc[0];
        Ls[kw][qw * 32 + 16 + lane] = lacc[1];
    }
    __syncthreads();

    #pragma unroll
    for (int n = 0; n < 4; ++n) {
        int qq = n * 16 + l15;
        float inv = 1.f / (Ls[0][qq] + Ls[1][qq]);
        #pragma unroll
        for (int m = 0; m < 2; ++m) {
            ushort4 ov;
            ov.x = f2bf(o[m][n][0] * inv);
            ov.y = f2bf(o[m][n][1] * inv);
            ov.z = f2bf(o[m][n][2] * inv);
            ov.w = f2bf(o[m][n][3] * inv);
            *(ushort4*)&AO[(size_t)(q0 + qq) * 4096 + h * 128
                           + w * 32 + m * 16 + quad * 4] = ov;
        }
    }
}

// ---------------------------------------------------------------------------
// inputs (fp32): x, rope, mask, cache_k, cache_v, wq, wk, wv, wo
// ws (u16 units): xb 8.4M | W0 16.8M (wq^T -> wo^T) | W1 4.2M (wk^T) |
//                 Qw 8.4M | Kc 4.2M | Vt 4.2M | AO 8.4M (wv^T parks here)
// ---------------------------------------------------------------------------
extern "C" void kernel_launch(void* const* d_in, const int* in_sizes, int n_in,
                              void* d_out, int out_size, void* d_ws, size_t ws_size,
                              hipStream_t stream)
{
    const float* x      = (const float*)d_in[0];
    const float* rope   = (const float*)d_in[1];
    const float* cacheK = (const float*)d_in[3];
    const float* cacheV = (const float*)d_in[4];
    const float* wq     = (const float*)d_in[5];
    const float* wk     = (const float*)d_in[6];
    const float* wv     = (const float*)d_in[7];
    const float* wo     = (const float*)d_in[8];
    float* out = (float*)d_out;

    u16* xb = (u16*)d_ws;                    // [2048][4096]
    u16* W0 = xb + (size_t)8388608;          // [4096][4096] wq^T, later wo^T
    u16* W1 = W0 + (size_t)16777216;         // [1024][4096] wk^T
    u16* Qw = W1 + (size_t)4194304;          // [2048][4096] (rope*scale)
    u16* Kc = Qw + (size_t)8388608;          // [8][4096][128]
    u16* Vt = Kc + (size_t)4194304;          // [8][128][4096]
    u16* AO = Vt + (size_t)4194304;          // [2048][4096]; wv^T parks here first
    u16* Wv = AO;                            // [1024][4096] until attn runs

    dim3 blk(256);
    cast_bf16<<<dim3(8192), blk, 0, stream>>>(x, xb, 2097152);
    tconv<<<dim3(128, 128), blk, 0, stream>>>(wq, W0, 4096, 4096);
    tconv<<<dim3(32, 128), blk, 0, stream>>>(wk, W1, 4096, 1024);
    tconv<<<dim3(32, 128), blk, 0, stream>>>(wv, Wv, 4096, 1024);
    gemm_qkv<<<dim3(48, 16), blk, 0, stream>>>(xb, W0, W1, Wv, Qw, Kc, Vt, rope);
    kcache_conv<<<dim3(2048), blk, 0, stream>>>(cacheK, Kc);
    vcache_conv<<<dim3(64, 4, 8), blk, 0, stream>>>(cacheV, Vt);
    attn_mfma<<<dim3(32, 32), blk, 0, stream>>>(Qw, Kc, Vt, AO);
    tconv<<<dim3(128, 128), blk, 0, stream>>>(wo, W0, 4096, 4096);
    gemm_wo<<<dim3(32, 16), blk, 0, stream>>>(AO, W0, out);
}

// Round 2
// 601.176 us; speedup vs baseline: 1.0195x; 1.0102x over previous
//
#include <hip/hip_runtime.h>

typedef unsigned short u16;
typedef unsigned int   u32;
typedef short  s16x8 __attribute__((ext_vector_type(8)));
typedef float  f32x4 __attribute__((ext_vector_type(4)));

__device__ __forceinline__ u16 f2bf(float f) {
    union { float f; u32 i; } x; x.f = f;
    u32 r = x.i + 0x7FFFu + ((x.i >> 16) & 1u);   // RNE
    return (u16)(r >> 16);
}

// async global->LDS, 16B per lane; lds base wave-uniform (HW adds lane*16)
__device__ __forceinline__ void gld16(const void* g, void* l) {
    __builtin_amdgcn_global_load_lds((const __attribute__((address_space(1))) void*)g,
                                     (__attribute__((address_space(3))) void*)l,
                                     16, 0, 0);
}

// ---------------------------------------------------------------------------
// elementwise fp32 -> bf16 cast
// ---------------------------------------------------------------------------
__global__ __launch_bounds__(256)
void cast_bf16(const float* __restrict__ in, u16* __restrict__ out, int n4) {
    int g = blockIdx.x * 256 + threadIdx.x;
    if (g >= n4) return;
    float4 v = ((const float4*)in)[g];
    ushort4 o; o.x = f2bf(v.x); o.y = f2bf(v.y); o.z = f2bf(v.z); o.w = f2bf(v.w);
    ((ushort4*)out)[g] = o;
}

// ---------------------------------------------------------------------------
// B[K][N] fp32 -> Bt[N][K] bf16, 32x32 LDS tile. grid(N/32, K/32)
// ---------------------------------------------------------------------------
__global__ __launch_bounds__(256)
void tconv(const float* __restrict__ B, u16* __restrict__ Bt, int K, int N) {
    __shared__ float T[32][33];
    int n0 = blockIdx.x * 32, k0 = blockIdx.y * 32;
    int t = threadIdx.x;
    int r = t >> 3, c4 = (t & 7) * 4;
    float4 v = *(const float4*)&B[(size_t)(k0 + r) * N + n0 + c4];
    T[r][c4 + 0] = v.x; T[r][c4 + 1] = v.y; T[r][c4 + 2] = v.z; T[r][c4 + 3] = v.w;
    __syncthreads();
    ushort4 o;
    o.x = f2bf(T[c4 + 0][r]); o.y = f2bf(T[c4 + 1][r]);
    o.z = f2bf(T[c4 + 2][r]); o.w = f2bf(T[c4 + 3][r]);
    *(ushort4*)&Bt[(size_t)(n0 + r) * K + k0 + c4] = o;
}

// ---------------------------------------------------------------------------
// cache_k fp32 [t][8][128] -> Kc bf16 [kh][4096_t][128] (tokens 0..2047)
// ---------------------------------------------------------------------------
__global__ __launch_bounds__(256)
void kcache_conv(const float* __restrict__ ck, u16* __restrict__ Kc) {
    int g = blockIdx.x * 256 + threadIdx.x;
    int d = (g & 31) * 4, kh = (g >> 5) & 7, t = g >> 8;
    float4 v = *(const float4*)&ck[(size_t)t * 1024 + kh * 128 + d];
    ushort4 o; o.x = f2bf(v.x); o.y = f2bf(v.y); o.z = f2bf(v.z); o.w = f2bf(v.w);
    *(ushort4*)&Kc[(size_t)kh * 524288 + (size_t)t * 128 + d] = o;
}

// ---------------------------------------------------------------------------
// cache_v fp32 [t][8][128] -> Vt bf16 [kh][128_hd][4096_t] (tokens 0..2047)
// ---------------------------------------------------------------------------
__global__ __launch_bounds__(256)
void vcache_conv(const float* __restrict__ cv, u16* __restrict__ Vt) {
    __shared__ float T[32][33];
    int t0 = blockIdx.x * 32, d0 = blockIdx.y * 32, kh = blockIdx.z;
    int t = threadIdx.x;
    int r = t >> 3, c4 = (t & 7) * 4;
    float4 v = *(const float4*)&cv[(size_t)(t0 + r) * 1024 + kh * 128 + d0 + c4];
    T[r][c4 + 0] = v.x; T[r][c4 + 1] = v.y; T[r][c4 + 2] = v.z; T[r][c4 + 3] = v.w;
    __syncthreads();
    ushort4 o;
    o.x = f2bf(T[c4 + 0][r]); o.y = f2bf(T[c4 + 1][r]);
    o.z = f2bf(T[c4 + 2][r]); o.w = f2bf(T[c4 + 3][r]);
    *(ushort4*)&Vt[(size_t)(kh * 128 + d0 + r) * 4096 + t0 + c4] = o;
}

// ---------------------------------------------------------------------------
// Shared MFMA GEMM main loop: acc[4][4] += A[m0..+128][K] @ Bt[0..128][K]^T.
// 128x128 tile, BK=32, gld16 staging, XOR-swizzled LDS (verified R3-R5).
// ---------------------------------------------------------------------------
__device__ __forceinline__ void gemm_core(const u16* __restrict__ A,
                                          const u16* __restrict__ Bt,
                                          int K, int m0,
                                          u16* As, u16* Bs, f32x4 acc[4][4])
{
    const int tid = threadIdx.x;
    const int lane = tid & 63, w = tid >> 6;
    const int quad = lane >> 4, l15 = lane & 15;
    const int mw = (w >> 1) * 64, nw = (w & 1) * 64;
    const int lrow = tid >> 2;
    const int lcol = ((tid & 3) ^ (lrow & 3)) * 8;
    const int rsw = l15 & 3;

    for (int k0 = 0; k0 < K; k0 += 32) {
        __syncthreads();
        gld16(A  + (size_t)(m0 +      lrow) * K + k0 + lcol, &As[w * 512]);
        gld16(A  + (size_t)(m0 + 64 + lrow) * K + k0 + lcol, &As[2048 + w * 512]);
        gld16(Bt + (size_t)(           lrow) * K + k0 + lcol, &Bs[w * 512]);
        gld16(Bt + (size_t)(      64 + lrow) * K + k0 + lcol, &Bs[2048 + w * 512]);
        __syncthreads();
        s16x8 af[4], bf[4];
        #pragma unroll
        for (int i = 0; i < 4; ++i)
            af[i] = *(const s16x8*)&As[(mw + i * 16 + l15) * 32 + (quad ^ rsw) * 8];
        #pragma unroll
        for (int j = 0; j < 4; ++j)
            bf[j] = *(const s16x8*)&Bs[(nw + j * 16 + l15) * 32 + (quad ^ rsw) * 8];
        #pragma unroll
        for (int i = 0; i < 4; ++i)
            #pragma unroll
            for (int j = 0; j < 4; ++j)
                acc[i][j] = __builtin_amdgcn_mfma_f32_16x16x32_bf16(
                    af[i], bf[j], acc[i][j], 0, 0, 0);
    }
}

// ---------------------------------------------------------------------------
// Fused QKV GEMM: N = 4096(Q) + 1024(K) + 1024(V) = 6144, grid(48,16).
// ---------------------------------------------------------------------------
__global__ __launch_bounds__(256, 2)
void gemm_qkv(const u16* __restrict__ A, const u16* __restrict__ Wq,
              const u16* __restrict__ Wk, const u16* __restrict__ Wv,
              u16* __restrict__ Qw, u16* __restrict__ Kc, u16* __restrict__ Vt,
              const float* __restrict__ rope)
{
    __shared__ u16 As[128 * 32];
    __shared__ u16 Bs[128 * 32];
    const int m0 = blockIdx.y * 128, n0 = blockIdx.x * 128;

    const u16* Bt;
    if (n0 < 4096)       Bt = Wq + (size_t)n0 * 4096;
    else if (n0 < 5120)  Bt = Wk + (size_t)(n0 - 4096) * 4096;
    else                 Bt = Wv + (size_t)(n0 - 5120) * 4096;

    f32x4 acc[4][4];
    #pragma unroll
    for (int i = 0; i < 4; ++i)
        #pragma unroll
        for (int j = 0; j < 4; ++j) acc[i][j] = (f32x4)0.f;

    gemm_core(A, Bt, 4096, m0, As, Bs, acc);

    const int lane = threadIdx.x & 63, w = threadIdx.x >> 6;
    const int quad = lane >> 4, l15 = lane & 15;
    const int mw = (w >> 1) * 64, nw = (w & 1) * 64;

    #pragma unroll
    for (int i = 0; i < 4; ++i) {
        #pragma unroll
        for (int j = 0; j < 4; ++j) {
            int mm = m0 + mw + i * 16 + quad * 4;
            int nn = n0 + nw + j * 16 + l15;
            if (nn < 4096) {
                #pragma unroll
                for (int r = 0; r < 4; ++r)
                    Qw[(size_t)(mm + r) * 4096 + nn] =
                        f2bf(acc[i][j][r] * rope[(size_t)(mm + r) * 128 + (nn & 127)]
                             * 0.08838834764831845f);
            } else if (nn < 5120) {
                #pragma unroll
                for (int r = 0; r < 4; ++r)
                    Kc[(size_t)((nn - 4096) >> 7) * 524288
                       + (size_t)(2048 + mm + r) * 128 + (nn & 127)] =
                        f2bf(acc[i][j][r] * rope[(size_t)(mm + r) * 128 + (nn & 127)]);
            } else {
                ushort4 o;
                o.x = f2bf(acc[i][j][0]); o.y = f2bf(acc[i][j][1]);
                o.z = f2bf(acc[i][j][2]); o.w = f2bf(acc[i][j][3]);
                *(ushort4*)&Vt[(size_t)(nn - 5120) * 4096 + 2048 + mm] = o;
            }
        }
    }
}

// ---------------------------------------------------------------------------
// Output GEMM: out = AO @ wo^T, fp32 out. grid(32,16).
// ---------------------------------------------------------------------------
__global__ __launch_bounds__(256, 2)
void gemm_wo(const u16* __restrict__ A, const u16* __restrict__ Bt,
             float* __restrict__ C)
{
    __shared__ u16 As[128 * 32];
    __shared__ u16 Bs[128 * 32];
    const int m0 = blockIdx.y * 128, n0 = blockIdx.x * 128;

    f32x4 acc[4][4];
    #pragma unroll
    for (int i = 0; i < 4; ++i)
        #pragma unroll
        for (int j = 0; j < 4; ++j) acc[i][j] = (f32x4)0.f;

    gemm_core(A, Bt + (size_t)n0 * 4096, 4096, m0, As, Bs, acc);

    const int lane = threadIdx.x & 63, w = threadIdx.x >> 6;
    const int quad = lane >> 4, l15 = lane & 15;
    const int mw = (w >> 1) * 64, nw = (w & 1) * 64;

    #pragma unroll
    for (int i = 0; i < 4; ++i)
        #pragma unroll
        for (int j = 0; j < 4; ++j) {
            int mm = m0 + mw + i * 16 + quad * 4;
            int nn = n0 + nw + j * 16 + l15;
            #pragma unroll
            for (int r = 0; r < 4; ++r)
                C[(size_t)(mm + r) * 4096 + nn] = acc[i][j][r];
        }
}

// ---------------------------------------------------------------------------
// MFMA flash attention, R7: occupancy play.
//   R1 showed latency-bound at 19% occupancy (2 blk/CU, LDS 75 KB): MfmaUtil
//   24%, HBM 6%, nothing saturated. Fix: halve KV tile 64->32 keys.
//   LDS = Ks dbuf 16K + Vs dbuf 16K + Pb 5K + Ls 0.5K = 38.4 KB -> 4 blk/CU
//   = 4 waves/SIMD (VGPR 88 <= 128, launch_bounds(256,4)). Per-work LDS/MFMA/
//   exp counts invariant; barrier count doubles but 4-way block TLP hides it.
//   XCD remap: bid%8 = kh -> each kh's 2MB K/V pinned to one XCD's 4MB L2.
//   Wave roles per 32-key tile: S wave (kw,qw) = 16k x 32q (8 MFMA, kf only);
//   PV wave w = hd[32w,+32) x 64q, one K=32 pass (8 MFMA). Pb stride 40 u16
//   (2-way banks = free). Q in registers (R6). 2-deep staging pipeline (R6):
//   issue tile t+1 after top barrier, drain at next top barrier; mid Pb
//   barrier is lgkmcnt-only so gld16s stay in flight.
// ---------------------------------------------------------------------------
__global__ __launch_bounds__(256, 4)
void attn_mfma(const u16* __restrict__ Qw, const u16* __restrict__ Kc,
               const u16* __restrict__ Vt, u16* __restrict__ AO)
{
    __shared__ u16 Ks[2][32 * 128];  // [buf][key][hd], rows 256B, swizzled
    __shared__ u16 Vs[2][128 * 32];  // [buf][hd][key], rows 64B, swizzled
    __shared__ u16 Pb[64 * 40];      // [q][key], stride 80B
    __shared__ float Ls[2][64];

    const int tid = threadIdx.x;
    const int lane = tid & 63, w = tid >> 6;
    const int quad = lane >> 4, l15 = lane & 15;

    // XCD-aware remap: all 128 blocks of one kh land on one XCD (bid%8 = kh)
    const int bid = blockIdx.x + 32 * blockIdx.y;      // 0..1023
    const int kh = bid & 7;
    const int inner = bid >> 3;                        // 0..127
    const int h = kh * 4 + (inner & 3);
    const int q0 = (inner >> 2) * 64;

    const int kw = w & 1, qw = w >> 1;
    const size_t kvb = (size_t)kh * 524288;

    // Q fragments -> registers, once.
    s16x8 qreg[2][4];
    #pragma unroll
    for (int n = 0; n < 2; ++n)
        #pragma unroll
        for (int ks = 0; ks < 4; ++ks)
            qreg[n][ks] = *(const s16x8*)&Qw[(size_t)(q0 + qw * 32 + n * 16 + l15) * 4096
                                             + h * 128 + ks * 32 + quad * 8];

    f32x4 o[2][4];
    #pragma unroll
    for (int m = 0; m < 2; ++m)
        #pragma unroll
        for (int n = 0; n < 4; ++n) o[m][n] = (f32x4)0.f;
    float lacc[2] = {0.f, 0.f};

    // staging roles (swizzled global column chunks; chunk = 16B)
    // K: 16 chunks/row, swizzle ^(row&15). V: 4 chunks/row, swizzle ^((row>>1)&3)
    const int krow = tid >> 4, kcol = ((tid & 15) ^ (krow & 15)) * 8;
    const int vrow = tid >> 2, vcol = ((tid & 3) ^ ((vrow >> 1) & 3)) * 8;

    const u16* kpg = Kc + kvb + (size_t)krow * 128 + kcol;
    const u16* vpg = Vt + kvb + (size_t)vrow * 4096 + vcol;

    const int kend = 2112 + q0;     // last needed key = 2048+q0+63

    // prologue: stage tile 0 into buffer 0
    #pragma unroll
    for (int i = 0; i < 2; ++i)
        gld16(kpg + i * 2048, &Ks[0][i * 2048 + w * 512]);
    #pragma unroll
    for (int i = 0; i < 2; ++i)
        gld16(vpg + (size_t)i * 262144, &Vs[0][i * 2048 + w * 512]);

    int cur = 0;
    for (int t0 = 0; t0 < kend; t0 += 32, cur ^= 1) {
        // full drain: buf[cur] staged & visible; prior tile's LDS reads done
        __syncthreads();

        // issue next tile's staging into buf[cur^1] (in flight across body)
        const int t1 = t0 + 32;
        if (t1 < kend) {
            #pragma unroll
            for (int i = 0; i < 2; ++i)
                gld16(kpg + (size_t)t1 * 128 + i * 2048,
                      &Ks[cur ^ 1][i * 2048 + w * 512]);
            #pragma unroll
            for (int i = 0; i < 2; ++i)
                gld16(vpg + (size_t)i * 262144 + t1,
                      &Vs[cur ^ 1][i * 2048 + w * 512]);
        }

        // ---- S phase: wave (kw,qw) -> keys [16kw,+16) x q [32qw,+32) ----
        f32x4 sc[2];
        sc[0] = (f32x4)0.f; sc[1] = (f32x4)0.f;
        #pragma unroll
        for (int ks = 0; ks < 4; ++ks) {
            int kc8 = (((ks * 4 + quad) ^ l15) & 15) * 8;
            s16x8 kf = *(const s16x8*)&Ks[cur][(kw * 16 + l15) * 128 + kc8];
            sc[0] = __builtin_amdgcn_mfma_f32_16x16x32_bf16(kf, qreg[0][ks], sc[0], 0, 0, 0);
            sc[1] = __builtin_amdgcn_mfma_f32_16x16x32_bf16(kf, qreg[1][ks], sc[1], 0, 0, 0);
        }

        const bool maskt = (t0 + 31 > 2048 + q0);
        #pragma unroll
        for (int n2 = 0; n2 < 2; ++n2) {
            float e0 = __expf(sc[n2][0]);
            float e1 = __expf(sc[n2][1]);
            float e2 = __expf(sc[n2][2]);
            float e3 = __expf(sc[n2][3]);
            if (maskt) {
                int key = t0 + kw * 16 + quad * 4;
                int qv  = q0 + qw * 32 + n2 * 16 + l15;
                if (key + 0 >= 2048 && key + 0 - 2048 > qv) e0 = 0.f;
                if (key + 1 >= 2048 && key + 1 - 2048 > qv) e1 = 0.f;
                if (key + 2 >= 2048 && key + 2 - 2048 > qv) e2 = 0.f;
                if (key + 3 >= 2048 && key + 3 - 2048 > qv) e3 = 0.f;
            }
            lacc[n2] += (e0 + e1) + (e2 + e3);
            uint2 pk;
            pk.x = (u32)f2bf(e0) | ((u32)f2bf(e1) << 16);
            pk.y = (u32)f2bf(e2) | ((u32)f2bf(e3) << 16);
            *(uint2*)&Pb[(qw * 32 + n2 * 16 + l15) * 40 + kw * 16 + quad * 4] = pk;
        }

        // Pb-ready barrier: DS ordering only -- do NOT drain vmcnt
        asm volatile("s_waitcnt lgkmcnt(0)" ::: "memory");
        __builtin_amdgcn_s_barrier();
        asm volatile("" ::: "memory");

        // ---- PV phase: wave w -> hd [32w,+32) x all 64 q, k = 32 keys ----
        s16x8 vf[2];
        #pragma unroll
        for (int m = 0; m < 2; ++m) {
            int vr = w * 32 + m * 16 + l15;
            int vc = (quad ^ ((vr >> 1) & 3)) * 8;
            vf[m] = *(const s16x8*)&Vs[cur][vr * 32 + vc];
        }
        #pragma unroll
        for (int n = 0; n < 4; ++n) {
            s16x8 pf = *(const s16x8*)&Pb[(n * 16 + l15) * 40 + quad * 8];
            o[0][n] = __builtin_amdgcn_mfma_f32_16x16x32_bf16(vf[0], pf, o[0][n], 0, 0, 0);
            o[1][n] = __builtin_amdgcn_mfma_f32_16x16x32_bf16(vf[1], pf, o[1][n], 0, 0, 0);
        }
    }

    // L totals: reduce over quads, publish per (kw, q), sum the two kw halves
    lacc[0] += __shfl_xor(lacc[0], 16); lacc[0] += __shfl_xor(lacc[0], 32);
    lacc[1] += __shfl_xor(lacc[1], 16); lacc[1] += __shfl_xor(lacc[1], 32);
    if (lane < 16) {
        Ls[kw][qw * 32 +      lane] = lacc[0];
        Ls[kw][qw * 32 + 16 + lane] = lacc[1];
    }
    __syncthreads();

    #pragma unroll
    for (int n = 0; n < 4; ++n) {
        int qq = n * 16 + l15;
        float inv = 1.f / (Ls[0][qq] + Ls[1][qq]);
        #pragma unroll
        for (int m = 0; m < 2; ++m) {
            ushort4 ov;
            ov.x = f2bf(o[m][n][0] * inv);
            ov.y = f2bf(o[m][n][1] * inv);
            ov.z = f2bf(o[m][n][2] * inv);
            ov.w = f2bf(o[m][n][3] * inv);
            *(ushort4*)&AO[(size_t)(q0 + qq) * 4096 + h * 128
                           + w * 32 + m * 16 + quad * 4] = ov;
        }
    }
}

// ---------------------------------------------------------------------------
// inputs (fp32): x, rope, mask, cache_k, cache_v, wq, wk, wv, wo
// ws (u16 units): xb 8.4M | W0 16.8M (wq^T -> wo^T) | W1 4.2M (wk^T) |
//                 Qw 8.4M | Kc 4.2M | Vt 4.2M | AO 8.4M (wv^T parks here)
// ---------------------------------------------------------------------------
extern "C" void kernel_launch(void* const* d_in, const int* in_sizes, int n_in,
                              void* d_out, int out_size, void* d_ws, size_t ws_size,
                              hipStream_t stream)
{
    const float* x      = (const float*)d_in[0];
    const float* rope   = (const float*)d_in[1];
    const float* cacheK = (const float*)d_in[3];
    const float* cacheV = (const float*)d_in[4];
    const float* wq     = (const float*)d_in[5];
    const float* wk     = (const float*)d_in[6];
    const float* wv     = (const float*)d_in[7];
    const float* wo     = (const float*)d_in[8];
    float* out = (float*)d_out;

    u16* xb = (u16*)d_ws;                    // [2048][4096]
    u16* W0 = xb + (size_t)8388608;          // [4096][4096] wq^T, later wo^T
    u16* W1 = W0 + (size_t)16777216;         // [1024][4096] wk^T
    u16* Qw = W1 + (size_t)4194304;          // [2048][4096] (rope*scale)
    u16* Kc = Qw + (size_t)8388608;          // [8][4096][128]
    u16* Vt = Kc + (size_t)4194304;          // [8][128][4096]
    u16* AO = Vt + (size_t)4194304;          // [2048][4096]; wv^T parks here first
    u16* Wv = AO;                            // [1024][4096] until attn runs

    dim3 blk(256);
    cast_bf16<<<dim3(8192), blk, 0, stream>>>(x, xb, 2097152);
    tconv<<<dim3(128, 128), blk, 0, stream>>>(wq, W0, 4096, 4096);
    tconv<<<dim3(32, 128), blk, 0, stream>>>(wk, W1, 4096, 1024);
    tconv<<<dim3(32, 128), blk, 0, stream>>>(wv, Wv, 4096, 1024);
    gemm_qkv<<<dim3(48, 16), blk, 0, stream>>>(xb, W0, W1, Wv, Qw, Kc, Vt, rope);
    kcache_conv<<<dim3(2048), blk, 0, stream>>>(cacheK, Kc);
    vcache_conv<<<dim3(64, 4, 8), blk, 0, stream>>>(cacheV, Vt);
    attn_mfma<<<dim3(32, 32), blk, 0, stream>>>(Qw, Kc, Vt, AO);
    tconv<<<dim3(128, 128), blk, 0, stream>>>(wo, W0, 4096, 4096);
    gemm_wo<<<dim3(32, 16), blk, 0, stream>>>(AO, W0, out);
}

// Round 3
// 592.876 us; speedup vs baseline: 1.0337x; 1.0140x over previous
//
#include <hip/hip_runtime.h>

typedef unsigned short u16;
typedef unsigned int   u32;
typedef short  s16x8 __attribute__((ext_vector_type(8)));
typedef float  f32x4 __attribute__((ext_vector_type(4)));

__device__ __forceinline__ u16 f2bf(float f) {
    union { float f; u32 i; } x; x.f = f;
    u32 r = x.i + 0x7FFFu + ((x.i >> 16) & 1u);   // RNE
    return (u16)(r >> 16);
}

// async global->LDS, 16B per lane; lds base wave-uniform (HW adds lane*16)
__device__ __forceinline__ void gld16(const void* g, void* l) {
    __builtin_amdgcn_global_load_lds((const __attribute__((address_space(1))) void*)g,
                                     (__attribute__((address_space(3))) void*)l,
                                     16, 0, 0);
}

// ---------------------------------------------------------------------------
// elementwise fp32 -> bf16 cast
// ---------------------------------------------------------------------------
__global__ __launch_bounds__(256)
void cast_bf16(const float* __restrict__ in, u16* __restrict__ out, int n4) {
    int g = blockIdx.x * 256 + threadIdx.x;
    if (g >= n4) return;
    float4 v = ((const float4*)in)[g];
    ushort4 o; o.x = f2bf(v.x); o.y = f2bf(v.y); o.z = f2bf(v.z); o.w = f2bf(v.w);
    ((ushort4*)out)[g] = o;
}

// ---------------------------------------------------------------------------
// B[K][N] fp32 -> Bt[N][K] bf16, 32x32 LDS tile. grid(N/32, K/32)
// ---------------------------------------------------------------------------
__global__ __launch_bounds__(256)
void tconv(const float* __restrict__ B, u16* __restrict__ Bt, int K, int N) {
    __shared__ float T[32][33];
    int n0 = blockIdx.x * 32, k0 = blockIdx.y * 32;
    int t = threadIdx.x;
    int r = t >> 3, c4 = (t & 7) * 4;
    float4 v = *(const float4*)&B[(size_t)(k0 + r) * N + n0 + c4];
    T[r][c4 + 0] = v.x; T[r][c4 + 1] = v.y; T[r][c4 + 2] = v.z; T[r][c4 + 3] = v.w;
    __syncthreads();
    ushort4 o;
    o.x = f2bf(T[c4 + 0][r]); o.y = f2bf(T[c4 + 1][r]);
    o.z = f2bf(T[c4 + 2][r]); o.w = f2bf(T[c4 + 3][r]);
    *(ushort4*)&Bt[(size_t)(n0 + r) * K + k0 + c4] = o;
}

// ---------------------------------------------------------------------------
// cache_k fp32 [t][8][128] -> Kc bf16 [kh][4096_t][128] (tokens 0..2047)
// ---------------------------------------------------------------------------
__global__ __launch_bounds__(256)
void kcache_conv(const float* __restrict__ ck, u16* __restrict__ Kc) {
    int g = blockIdx.x * 256 + threadIdx.x;
    int d = (g & 31) * 4, kh = (g >> 5) & 7, t = g >> 8;
    float4 v = *(const float4*)&ck[(size_t)t * 1024 + kh * 128 + d];
    ushort4 o; o.x = f2bf(v.x); o.y = f2bf(v.y); o.z = f2bf(v.z); o.w = f2bf(v.w);
    *(ushort4*)&Kc[(size_t)kh * 524288 + (size_t)t * 128 + d] = o;
}

// ---------------------------------------------------------------------------
// cache_v fp32 [t][8][128] -> Vt bf16 [kh][128_hd][4096_t] (tokens 0..2047)
// ---------------------------------------------------------------------------
__global__ __launch_bounds__(256)
void vcache_conv(const float* __restrict__ cv, u16* __restrict__ Vt) {
    __shared__ float T[32][33];
    int t0 = blockIdx.x * 32, d0 = blockIdx.y * 32, kh = blockIdx.z;
    int t = threadIdx.x;
    int r = t >> 3, c4 = (t & 7) * 4;
    float4 v = *(const float4*)&cv[(size_t)(t0 + r) * 1024 + kh * 128 + d0 + c4];
    T[r][c4 + 0] = v.x; T[r][c4 + 1] = v.y; T[r][c4 + 2] = v.z; T[r][c4 + 3] = v.w;
    __syncthreads();
    ushort4 o;
    o.x = f2bf(T[c4 + 0][r]); o.y = f2bf(T[c4 + 1][r]);
    o.z = f2bf(T[c4 + 2][r]); o.w = f2bf(T[c4 + 3][r]);
    *(ushort4*)&Vt[(size_t)(kh * 128 + d0 + r) * 4096 + t0 + c4] = o;
}

// ---------------------------------------------------------------------------
// Shared MFMA GEMM main loop: acc[4][4] += A[m0..+128][K] @ Bt[0..128][K]^T.
// 128x128 tile, BK=32, gld16 staging, XOR-swizzled LDS (verified R3-R5).
// ---------------------------------------------------------------------------
__device__ __forceinline__ void gemm_core(const u16* __restrict__ A,
                                          const u16* __restrict__ Bt,
                                          int K, int m0,
                                          u16* As, u16* Bs, f32x4 acc[4][4])
{
    const int tid = threadIdx.x;
    const int lane = tid & 63, w = tid >> 6;
    const int quad = lane >> 4, l15 = lane & 15;
    const int mw = (w >> 1) * 64, nw = (w & 1) * 64;
    const int lrow = tid >> 2;
    const int lcol = ((tid & 3) ^ (lrow & 3)) * 8;
    const int rsw = l15 & 3;

    for (int k0 = 0; k0 < K; k0 += 32) {
        __syncthreads();
        gld16(A  + (size_t)(m0 +      lrow) * K + k0 + lcol, &As[w * 512]);
        gld16(A  + (size_t)(m0 + 64 + lrow) * K + k0 + lcol, &As[2048 + w * 512]);
        gld16(Bt + (size_t)(           lrow) * K + k0 + lcol, &Bs[w * 512]);
        gld16(Bt + (size_t)(      64 + lrow) * K + k0 + lcol, &Bs[2048 + w * 512]);
        __syncthreads();
        s16x8 af[4], bf[4];
        #pragma unroll
        for (int i = 0; i < 4; ++i)
            af[i] = *(const s16x8*)&As[(mw + i * 16 + l15) * 32 + (quad ^ rsw) * 8];
        #pragma unroll
        for (int j = 0; j < 4; ++j)
            bf[j] = *(const s16x8*)&Bs[(nw + j * 16 + l15) * 32 + (quad ^ rsw) * 8];
        #pragma unroll
        for (int i = 0; i < 4; ++i)
            #pragma unroll
            for (int j = 0; j < 4; ++j)
                acc[i][j] = __builtin_amdgcn_mfma_f32_16x16x32_bf16(
                    af[i], bf[j], acc[i][j], 0, 0, 0);
    }
}

// ---------------------------------------------------------------------------
// Fused QKV GEMM: N = 4096(Q) + 1024(K) + 1024(V) = 6144, grid(48,16).
// ---------------------------------------------------------------------------
__global__ __launch_bounds__(256, 2)
void gemm_qkv(const u16* __restrict__ A, const u16* __restrict__ Wq,
              const u16* __restrict__ Wk, const u16* __restrict__ Wv,
              u16* __restrict__ Qw, u16* __restrict__ Kc, u16* __restrict__ Vt,
              const float* __restrict__ rope)
{
    __shared__ u16 As[128 * 32];
    __shared__ u16 Bs[128 * 32];
    const int m0 = blockIdx.y * 128, n0 = blockIdx.x * 128;

    const u16* Bt;
    if (n0 < 4096)       Bt = Wq + (size_t)n0 * 4096;
    else if (n0 < 5120)  Bt = Wk + (size_t)(n0 - 4096) * 4096;
    else                 Bt = Wv + (size_t)(n0 - 5120) * 4096;

    f32x4 acc[4][4];
    #pragma unroll
    for (int i = 0; i < 4; ++i)
        #pragma unroll
        for (int j = 0; j < 4; ++j) acc[i][j] = (f32x4)0.f;

    gemm_core(A, Bt, 4096, m0, As, Bs, acc);

    const int lane = threadIdx.x & 63, w = threadIdx.x >> 6;
    const int quad = lane >> 4, l15 = lane & 15;
    const int mw = (w >> 1) * 64, nw = (w & 1) * 64;

    #pragma unroll
    for (int i = 0; i < 4; ++i) {
        #pragma unroll
        for (int j = 0; j < 4; ++j) {
            int mm = m0 + mw + i * 16 + quad * 4;
            int nn = n0 + nw + j * 16 + l15;
            if (nn < 4096) {
                #pragma unroll
                for (int r = 0; r < 4; ++r)
                    Qw[(size_t)(mm + r) * 4096 + nn] =
                        f2bf(acc[i][j][r] * rope[(size_t)(mm + r) * 128 + (nn & 127)]
                             * 0.08838834764831845f);
            } else if (nn < 5120) {
                #pragma unroll
                for (int r = 0; r < 4; ++r)
                    Kc[(size_t)((nn - 4096) >> 7) * 524288
                       + (size_t)(2048 + mm + r) * 128 + (nn & 127)] =
                        f2bf(acc[i][j][r] * rope[(size_t)(mm + r) * 128 + (nn & 127)]);
            } else {
                ushort4 o;
                o.x = f2bf(acc[i][j][0]); o.y = f2bf(acc[i][j][1]);
                o.z = f2bf(acc[i][j][2]); o.w = f2bf(acc[i][j][3]);
                *(ushort4*)&Vt[(size_t)(nn - 5120) * 4096 + 2048 + mm] = o;
            }
        }
    }
}

// ---------------------------------------------------------------------------
// Output GEMM: out = AO @ wo^T, fp32 out. grid(32,16).
// ---------------------------------------------------------------------------
__global__ __launch_bounds__(256, 2)
void gemm_wo(const u16* __restrict__ A, const u16* __restrict__ Bt,
             float* __restrict__ C)
{
    __shared__ u16 As[128 * 32];
    __shared__ u16 Bs[128 * 32];
    const int m0 = blockIdx.y * 128, n0 = blockIdx.x * 128;

    f32x4 acc[4][4];
    #pragma unroll
    for (int i = 0; i < 4; ++i)
        #pragma unroll
        for (int j = 0; j < 4; ++j) acc[i][j] = (f32x4)0.f;

    gemm_core(A, Bt + (size_t)n0 * 4096, 4096, m0, As, Bs, acc);

    const int lane = threadIdx.x & 63, w = threadIdx.x >> 6;
    const int quad = lane >> 4, l15 = lane & 15;
    const int mw = (w >> 1) * 64, nw = (w & 1) * 64;

    #pragma unroll
    for (int i = 0; i < 4; ++i)
        #pragma unroll
        for (int j = 0; j < 4; ++j) {
            int mm = m0 + mw + i * 16 + quad * 4;
            int nn = n0 + nw + j * 16 + l15;
            #pragma unroll
            for (int r = 0; r < 4; ++r)
                C[(size_t)(mm + r) * 4096 + nn] = acc[i][j][r];
        }
}

// ---------------------------------------------------------------------------
// MFMA flash attention, R8: cross-tile S/PV software pipeline.
//   R2 was latency-bound on the serial per-tile chain (barrier -> S -> mid
//   barrier -> PV), all pipes <45%. Fix: double-buffer Pb and compute PV(t-1)
//   in iteration t. The Pb(t) write -> Pb(t) read dependency crosses the next
//   top barrier, so the mid-tile barrier is DELETED (1 barrier/tile) and
//   S(t) / PV(t-1) are fully independent within the body -> compiler issues
//   all kf/vf/pf loads right after the barrier, MFMA+VALU+LDS overlap.
//   Staging schedule: iter t stages K(t+1) and V(t) (V read one iter later).
//   LDS = Ks dbuf 16K + Vs dbuf 16K + Pb dbuf 8K = 40960 B exactly -> 4
//   blk/CU (Ls overlaid on dead KsBuf post-loop). Pb stride 32 u16 (no pad,
//   forced by budget) with 16B-chunk XOR swizzle (chunk ^= q&3): enumerated
//   even bank spread on both uint2 writes and b128 reads.
//   bf16 pack via v_cvt_pk_bf16_f32 (RNE, same result as manual f2bf).
//   Q in registers (R6); XCD remap kh=bid&7 (R7, FETCH 68->16 MB verified).
// ---------------------------------------------------------------------------
__global__ __launch_bounds__(256, 4)
void attn_mfma(const u16* __restrict__ Qw, const u16* __restrict__ Kc,
               const u16* __restrict__ Vt, u16* __restrict__ AO)
{
    __shared__ u16 KsBuf[2][32 * 128];  // [buf][key][hd], swizzled chunks
    __shared__ u16 VsBuf[2][128 * 32];  // [buf][hd][key], swizzled chunks
    __shared__ u16 PbBuf[2][64 * 32];   // [buf][q][key], chunk-XOR swizzled

    const int tid = threadIdx.x;
    const int lane = tid & 63, w = tid >> 6;
    const int quad = lane >> 4, l15 = lane & 15;

    // XCD-aware remap: all 128 blocks of one kh land on one XCD (bid%8 = kh)
    const int bid = blockIdx.x + 32 * blockIdx.y;      // 0..1023
    const int kh = bid & 7;
    const int inner = bid >> 3;                        // 0..127
    const int h = kh * 4 + (inner & 3);
    const int q0 = (inner >> 2) * 64;

    const int kw = w & 1, qw = w >> 1;
    const size_t kvb = (size_t)kh * 524288;

    // Q fragments -> registers, once.
    s16x8 qreg[2][4];
    #pragma unroll
    for (int n = 0; n < 2; ++n)
        #pragma unroll
        for (int ks = 0; ks < 4; ++ks)
            qreg[n][ks] = *(const s16x8*)&Qw[(size_t)(q0 + qw * 32 + n * 16 + l15) * 4096
                                             + h * 128 + ks * 32 + quad * 8];

    f32x4 o[2][4];
    #pragma unroll
    for (int m = 0; m < 2; ++m)
        #pragma unroll
        for (int n = 0; n < 4; ++n) o[m][n] = (f32x4)0.f;
    float lacc[2] = {0.f, 0.f};

    // staging roles (swizzled global column chunks; chunk = 16B)
    const int krow = tid >> 4, kcol = ((tid & 15) ^ (krow & 15)) * 8;
    const int vrow = tid >> 2, vcol = ((tid & 3) ^ ((vrow >> 1) & 3)) * 8;

    const u16* kpg = Kc + kvb + (size_t)krow * 128 + kcol;
    const u16* vpg = Vt + kvb + (size_t)vrow * 4096 + vcol;

    const int kend = 2112 + q0;     // last needed key = 2048+q0+63

    // buffer role pointers (swapped per iteration; never runtime-indexed)
    u16* ks_rd = &KsBuf[0][0]; u16* ks_st = &KsBuf[1][0];  // read t / stage t+1
    u16* vs_rd = &VsBuf[1][0]; u16* vs_st = &VsBuf[0][0];  // read t-1 / stage t
    u16* pb_wr = &PbBuf[0][0]; u16* pb_rd = &PbBuf[1][0];  // write t / read t-1

    // PV(t-1): wave w -> hd [32w,+32) x all 64 q, 32 keys
    auto PV = [&](const u16* vs, const u16* pb) {
        int vr0 = w * 32 + l15;
        int vr1 = w * 32 + 16 + l15;
        s16x8 vf0 = *(const s16x8*)&vs[vr0 * 32 + (quad ^ ((vr0 >> 1) & 3)) * 8];
        s16x8 vf1 = *(const s16x8*)&vs[vr1 * 32 + (quad ^ ((vr1 >> 1) & 3)) * 8];
        #pragma unroll
        for (int n = 0; n < 4; ++n) {
            int q = n * 16 + l15;
            s16x8 pf = *(const s16x8*)&pb[q * 32 + ((quad ^ (q & 3)) * 8)];
            o[0][n] = __builtin_amdgcn_mfma_f32_16x16x32_bf16(vf0, pf, o[0][n], 0, 0, 0);
            o[1][n] = __builtin_amdgcn_mfma_f32_16x16x32_bf16(vf1, pf, o[1][n], 0, 0, 0);
        }
    };

    // prologue: stage K(0) into ks_rd's buffer
    gld16(kpg,        &ks_rd[w * 512]);
    gld16(kpg + 2048, &ks_rd[2048 + w * 512]);

    for (int t0 = 0; t0 < kend; t0 += 32) {
        // top barrier: K(t) staged, V(t-1) staged, Pb(t-1) visible,
        // and all reads of the buffers we are about to overwrite are done.
        __syncthreads();

        // issue staging: K(t+1) -> ks_st, V(t) -> vs_st (drain at next top)
        if (t0 + 32 < kend) {
            gld16(kpg + (size_t)(t0 + 32) * 128,        &ks_st[w * 512]);
            gld16(kpg + (size_t)(t0 + 32) * 128 + 2048, &ks_st[2048 + w * 512]);
        }
        gld16(vpg + t0,          &vs_st[w * 512]);
        gld16(vpg + 262144 + t0, &vs_st[2048 + w * 512]);

        // ---- S(t): wave (kw,qw) -> keys [16kw,+16) x q [32qw,+32) ----
        f32x4 sc[2];
        sc[0] = (f32x4)0.f; sc[1] = (f32x4)0.f;
        #pragma unroll
        for (int ks = 0; ks < 4; ++ks) {
            int kc8 = (((ks * 4 + quad) ^ l15) & 15) * 8;
            s16x8 kf = *(const s16x8*)&ks_rd[(kw * 16 + l15) * 128 + kc8];
            sc[0] = __builtin_amdgcn_mfma_f32_16x16x32_bf16(kf, qreg[0][ks], sc[0], 0, 0, 0);
            sc[1] = __builtin_amdgcn_mfma_f32_16x16x32_bf16(kf, qreg[1][ks], sc[1], 0, 0, 0);
        }

        const bool maskt = (t0 + 31 > 2048 + q0);
        #pragma unroll
        for (int n2 = 0; n2 < 2; ++n2) {
            float e0 = __expf(sc[n2][0]);
            float e1 = __expf(sc[n2][1]);
            float e2 = __expf(sc[n2][2]);
            float e3 = __expf(sc[n2][3]);
            if (maskt) {
                int key = t0 + kw * 16 + quad * 4;
                int qv  = q0 + qw * 32 + n2 * 16 + l15;
                if (key + 0 >= 2048 && key + 0 - 2048 > qv) e0 = 0.f;
                if (key + 1 >= 2048 && key + 1 - 2048 > qv) e1 = 0.f;
                if (key + 2 >= 2048 && key + 2 - 2048 > qv) e2 = 0.f;
                if (key + 3 >= 2048 && key + 3 - 2048 > qv) e3 = 0.f;
            }
            lacc[n2] += (e0 + e1) + (e2 + e3);
            u32 p0, p1;
            asm("v_cvt_pk_bf16_f32 %0, %1, %2" : "=v"(p0) : "v"(e0), "v"(e1));
            asm("v_cvt_pk_bf16_f32 %0, %1, %2" : "=v"(p1) : "v"(e2), "v"(e3));
            // Pb[q][key], stride 32 u16; 16B-chunk XOR swizzle: chunk ^= q&3.
            // write = 8B half of chunk c0 = 2*kw + (quad>>1), half = quad&1.
            int q = qw * 32 + n2 * 16 + l15;
            uint2 pk; pk.x = p0; pk.y = p1;
            *(uint2*)&pb_wr[q * 32 + (((2 * kw + (quad >> 1)) ^ (q & 3)) * 8)
                            + (quad & 1) * 4] = pk;
        }

        // ---- PV(t-1): independent of S(t), no barrier needed ----
        if (t0) PV(vs_rd, pb_rd);

        // rotate buffer roles
        u16* tp;
        tp = ks_rd; ks_rd = ks_st; ks_st = tp;
        tp = vs_rd; vs_rd = vs_st; vs_st = tp;
        tp = pb_rd; pb_rd = pb_wr; pb_wr = tp;
    }

    // epilogue: PV of the final tile
    __syncthreads();
    PV(vs_rd, pb_rd);

    // L totals: reduce over quads, publish per (kw, q), sum the two kw halves.
    // Ls overlaid on KsBuf (dead after loop).
    float* Ls = (float*)&KsBuf[0][0];           // [2][64]
    lacc[0] += __shfl_xor(lacc[0], 16); lacc[0] += __shfl_xor(lacc[0], 32);
    lacc[1] += __shfl_xor(lacc[1], 16); lacc[1] += __shfl_xor(lacc[1], 32);
    if (lane < 16) {
        Ls[kw * 64 + qw * 32 +      lane] = lacc[0];
        Ls[kw * 64 + qw * 32 + 16 + lane] = lacc[1];
    }
    __syncthreads();

    #pragma unroll
    for (int n = 0; n < 4; ++n) {
        int qq = n * 16 + l15;
        float inv = 1.f / (Ls[qq] + Ls[64 + qq]);
        #pragma unroll
        for (int m = 0; m < 2; ++m) {
            ushort4 ov;
            ov.x = f2bf(o[m][n][0] * inv);
            ov.y = f2bf(o[m][n][1] * inv);
            ov.z = f2bf(o[m][n][2] * inv);
            ov.w = f2bf(o[m][n][3] * inv);
            *(ushort4*)&AO[(size_t)(q0 + qq) * 4096 + h * 128
                           + w * 32 + m * 16 + quad * 4] = ov;
        }
    }
}

// ---------------------------------------------------------------------------
// inputs (fp32): x, rope, mask, cache_k, cache_v, wq, wk, wv, wo
// ws (u16 units): xb 8.4M | W0 16.8M (wq^T -> wo^T) | W1 4.2M (wk^T) |
//                 Qw 8.4M | Kc 4.2M | Vt 4.2M | AO 8.4M (wv^T parks here)
// ---------------------------------------------------------------------------
extern "C" void kernel_launch(void* const* d_in, const int* in_sizes, int n_in,
                              void* d_out, int out_size, void* d_ws, size_t ws_size,
                              hipStream_t stream)
{
    const float* x      = (const float*)d_in[0];
    const float* rope   = (const float*)d_in[1];
    const float* cacheK = (const float*)d_in[3];
    const float* cacheV = (const float*)d_in[4];
    const float* wq     = (const float*)d_in[5];
    const float* wk     = (const float*)d_in[6];
    const float* wv     = (const float*)d_in[7];
    const float* wo     = (const float*)d_in[8];
    float* out = (float*)d_out;

    u16* xb = (u16*)d_ws;                    // [2048][4096]
    u16* W0 = xb + (size_t)8388608;          // [4096][4096] wq^T, later wo^T
    u16* W1 = W0 + (size_t)16777216;         // [1024][4096] wk^T
    u16* Qw = W1 + (size_t)4194304;          // [2048][4096] (rope*scale)
    u16* Kc = Qw + (size_t)8388608;          // [8][4096][128]
    u16* Vt = Kc + (size_t)4194304;          // [8][128][4096]
    u16* AO = Vt + (size_t)4194304;          // [2048][4096]; wv^T parks here first
    u16* Wv = AO;                            // [1024][4096] until attn runs

    dim3 blk(256);
    cast_bf16<<<dim3(8192), blk, 0, stream>>>(x, xb, 2097152);
    tconv<<<dim3(128, 128), blk, 0, stream>>>(wq, W0, 4096, 4096);
    tconv<<<dim3(32, 128), blk, 0, stream>>>(wk, W1, 4096, 1024);
    tconv<<<dim3(32, 128), blk, 0, stream>>>(wv, Wv, 4096, 1024);
    gemm_qkv<<<dim3(48, 16), blk, 0, stream>>>(xb, W0, W1, Wv, Qw, Kc, Vt, rope);
    kcache_conv<<<dim3(2048), blk, 0, stream>>>(cacheK, Kc);
    vcache_conv<<<dim3(64, 4, 8), blk, 0, stream>>>(cacheV, Vt);
    attn_mfma<<<dim3(32, 32), blk, 0, stream>>>(Qw, Kc, Vt, AO);
    tconv<<<dim3(128, 128), blk, 0, stream>>>(wo, W0, 4096, 4096);
    gemm_wo<<<dim3(32, 16), blk, 0, stream>>>(AO, W0, out);
}